// Round 4
// baseline (2355.259 us; speedup 1.0000x reference)
//
#include <hip/hip_runtime.h>
#include <stdint.h>

#define E_DIM 1024
#define SEQ 4096
#define BATCH 8

typedef unsigned short u16;
typedef __attribute__((ext_vector_type(8))) short bf16x8;
typedef __attribute__((ext_vector_type(4))) float f32x4;

static __device__ __forceinline__ float bf2f(u16 u){
  union { unsigned u; float f; } x; x.u = ((unsigned)u) << 16; return x.f;
}
static __device__ __forceinline__ u16 f2bf(float f){
  union { float f; unsigned u; } x; x.f = f;
  unsigned r = (x.u + 0x7fffu + ((x.u >> 16) & 1u)) >> 16;
  return (u16)r;
}
static __device__ __forceinline__ void lds_fence(){
  __asm__ volatile("s_waitcnt lgkmcnt(0)" ::: "memory");
}

// ---------------- convert fp32 -> bf16, 8 elements/thread ----------------
__global__ __launch_bounds__(256) void conv_f2b(
    const float* __restrict__ src, u16* __restrict__ dst)
{
  size_t i = ((size_t)blockIdx.x * 256 + threadIdx.x) * 8;
  float4 a = *(const float4*)(src + i);
  float4 b = *(const float4*)(src + i + 4);
  u16 tmp[8] __attribute__((aligned(16)));
  tmp[0] = f2bf(a.x); tmp[1] = f2bf(a.y); tmp[2] = f2bf(a.z); tmp[3] = f2bf(a.w);
  tmp[4] = f2bf(b.x); tmp[5] = f2bf(b.y); tmp[6] = f2bf(b.z); tmp[7] = f2bf(b.w);
  *(uint4*)(dst + i) = *(const uint4*)tmp;
}

// ---------------- prep: transpose 1024x1024 fp32 -> bf16 ----------------
// blockIdx.y: 0 -> W_kit -> Wt_kv rows [0,1024); 1 -> W_vit -> rows [1024,2048);
// 2 -> W_out -> Wt_out.
__global__ __launch_bounds__(256) void prep_transpose(
    const float* __restrict__ Wkit, const float* __restrict__ Wvit,
    const float* __restrict__ Wout, u16* __restrict__ Wt_kv,
    u16* __restrict__ Wt_out)
{
  __shared__ __align__(16) float sT[64][65];
  int m = blockIdx.y;
  const float* src = (m == 0) ? Wkit : (m == 1) ? Wvit : Wout;
  u16* dst = (m == 0) ? Wt_kv : (m == 1) ? (Wt_kv + 1024 * 1024) : Wt_out;
  int tile = blockIdx.x;            // 0..255
  int r0 = (tile & 15) * 64;        // src row base
  int c0 = (tile >> 4) * 64;        // src col base
  int t = threadIdx.x;
  #pragma unroll
  for (int it = 0; it < 4; ++it){
    int idx = t + it * 256;         // 0..1023
    int r = idx >> 4, cq = idx & 15;
    float4 v = *(const float4*)(src + (size_t)(r0 + r) * 1024 + c0 + cq * 4);
    sT[r][cq * 4 + 0] = v.x; sT[r][cq * 4 + 1] = v.y;
    sT[r][cq * 4 + 2] = v.z; sT[r][cq * 4 + 3] = v.w;
  }
  __syncthreads();
  #pragma unroll
  for (int it = 0; it < 2; ++it){
    int idx = t + it * 256;         // 0..511
    int c = idx >> 3, rb = idx & 7;
    u16 tmp[8] __attribute__((aligned(16)));
    #pragma unroll
    for (int j = 0; j < 8; ++j) tmp[j] = f2bf(sT[rb * 8 + j][c]);
    *(uint4*)(dst + (size_t)(c0 + c) * 1024 + r0 + rb * 8) = *(const uint4*)tmp;
  }
}

// ---------------- prep: pack biases [b_kit | b_vit] (fp32) ----------------
__global__ __launch_bounds__(256) void prep_bias(
    const float* __restrict__ bkit, const float* __restrict__ bvit,
    float* __restrict__ bkv)
{
  int i = blockIdx.x * 256 + threadIdx.x;  // 0..2047
  bkv[i] = (i < 1024) ? bkit[i] : bvit[i - 1024];
}

// ---------------- prep: k_ti (bf16, e-order) and v_ti (bf16, [d][kh]) ----------------
__global__ __launch_bounds__(1024) void prep_ti(
    const float* __restrict__ text,
    const float* __restrict__ Wk, const float* __restrict__ bk,
    const float* __restrict__ Wv, const float* __restrict__ bv,
    u16* __restrict__ kti, u16* __restrict__ vtiT)
{
  __shared__ __align__(16) float sT[1024];
  int b = blockIdx.x;
  int m = blockIdx.y;
  int e = threadIdx.x;
  const float* W = (m == 0) ? Wk : Wv;
  const float* bias = (m == 0) ? bk : bv;
  sT[e] = text[(size_t)b * 1024 + e];
  __syncthreads();
  float acc = bias[e];
  #pragma unroll 8
  for (int k = 0; k < 1024; ++k)
    acc += sT[k] * W[(size_t)k * 1024 + e];
  u16 r = f2bf(acc);
  if (m == 0) kti[(size_t)b * 1024 + e] = r;
  else {
    int kh = e >> 6, d = e & 63;
    vtiT[(size_t)b * 1024 + d * 16 + kh] = r;
  }
}

// ---------------- main GEMM: C[M,N] = A[M,K=1024] * Bt[N,K=1024]^T + bias ----------------
// m93-style: 128x128 tile, 256 threads (4 waves, 2x2 of 64x64), BK=64,
// VGPR staging (uint4 global load -> ds_write_b128), row-major LDS.
// A, Bt are bf16 (u16); bias fp32; C templated (u16 bf16 or float).
template <typename CT>
__global__ __launch_bounds__(256, 2) void gemm_bt(
    const u16* __restrict__ A, const u16* __restrict__ Bt,
    const float* __restrict__ bias, CT* __restrict__ C,
    int n_tiles, int G, int ldc)
{
  __shared__ __align__(16) u16 sA[128 * 64];
  __shared__ __align__(16) u16 sB[128 * 64];
  int bid = blockIdx.x;
  int gb = G * n_tiles;
  int g = bid / gb;
  int r = bid - g * gb;
  int mt = g * G + (r % G);
  int nt = r / G;
  int m0 = mt * 128, n0 = nt * 128;
  int tid = threadIdx.x;
  int w = tid >> 6, lane = tid & 63;
  int wm = w & 1, wn = w >> 1;
  int quad = lane >> 4, l15 = lane & 15;
  f32x4 acc[4][4];
  #pragma unroll
  for (int i = 0; i < 4; ++i)
    #pragma unroll
    for (int j = 0; j < 4; ++j)
      acc[i][j] = (f32x4){0.f, 0.f, 0.f, 0.f};
  const u16* Abase = A + (size_t)m0 * 1024;
  const u16* Bbase = Bt + (size_t)n0 * 1024;
  int sr = tid >> 3;      // 0..31 (staging row)
  int sc = tid & 7;       // 0..7  (staging col-chunk of 8 u16)
  for (int kt = 0; kt < 16; ++kt){
    int k0 = kt * 64;
    uint4 va[4], vb[4];
    #pragma unroll
    for (int i = 0; i < 4; ++i){
      int row = sr + i * 32;
      va[i] = *(const uint4*)(Abase + (size_t)row * 1024 + k0 + sc * 8);
      vb[i] = *(const uint4*)(Bbase + (size_t)row * 1024 + k0 + sc * 8);
    }
    __syncthreads();
    #pragma unroll
    for (int i = 0; i < 4; ++i){
      int row = sr + i * 32;
      *(uint4*)&sA[row * 64 + sc * 8] = va[i];
      *(uint4*)&sB[row * 64 + sc * 8] = vb[i];
    }
    __syncthreads();
    #pragma unroll
    for (int ks = 0; ks < 2; ++ks){
      bf16x8 af[4], bfr[4];
      #pragma unroll
      for (int mi = 0; mi < 4; ++mi){
        int rt = wm * 64 + mi * 16 + l15;
        af[mi] = *(const bf16x8*)(sA + rt * 64 + (ks * 4 + quad) * 8);
      }
      #pragma unroll
      for (int ni = 0; ni < 4; ++ni){
        int rt = wn * 64 + ni * 16 + l15;
        bfr[ni] = *(const bf16x8*)(sB + rt * 64 + (ks * 4 + quad) * 8);
      }
      #pragma unroll
      for (int mi = 0; mi < 4; ++mi)
        #pragma unroll
        for (int ni = 0; ni < 4; ++ni)
          acc[mi][ni] = __builtin_amdgcn_mfma_f32_16x16x32_bf16(
              af[mi], bfr[ni], acc[mi][ni], 0, 0, 0);
    }
  }
  #pragma unroll
  for (int ni = 0; ni < 4; ++ni){
    int col = n0 + wn * 64 + ni * 16 + l15;
    float bv = bias[col];
    #pragma unroll
    for (int mi = 0; mi < 4; ++mi){
      int row0 = m0 + wm * 64 + mi * 16 + quad * 4;
      #pragma unroll
      for (int rg = 0; rg < 4; ++rg){
        float v = acc[mi][ni][rg] + bv;
        if constexpr (sizeof(CT) == 2)
          C[(size_t)(row0 + rg) * ldc + col] = (CT)f2bf(v);
        else
          C[(size_t)(row0 + rg) * ldc + col] = (CT)v;
      }
    }
  }
}

// ---------------- attention: one wave per row, 4 rows per wave ----------------
static __device__ __forceinline__ void softmax16(const f32x4& s, float* p){
  #pragma unroll
  for (int g = 0; g < 4; ++g){
    float v = s[g] * 0.125f;       // 1/sqrt(64)
    float m = v;
    m = fmaxf(m, __shfl_xor(m, 1, 16));
    m = fmaxf(m, __shfl_xor(m, 2, 16));
    m = fmaxf(m, __shfl_xor(m, 4, 16));
    m = fmaxf(m, __shfl_xor(m, 8, 16));
    float e = __expf(v - m);
    float t = e;
    t += __shfl_xor(t, 1, 16);
    t += __shfl_xor(t, 2, 16);
    t += __shfl_xor(t, 4, 16);
    t += __shfl_xor(t, 8, 16);
    p[g] = e / t;
  }
}

__global__ __launch_bounds__(256) void attn_kernel(
    const u16* __restrict__ img, const u16* __restrict__ text,
    const u16* __restrict__ kv, const u16* __restrict__ kti,
    const u16* __restrict__ vtiT, u16* __restrict__ attn, int b0)
{
  __shared__ __align__(16) u16 sP[4][16 * 32];
  int tid = threadIdx.x;
  int w = tid >> 6, lane = tid & 63;
  int quad = lane >> 4, l15 = lane & 15;
  u16* sPw = sP[w];
  const f32x4 fz = {0.f, 0.f, 0.f, 0.f};
  const bf16x8 bz = {0, 0, 0, 0, 0, 0, 0, 0};
  int rbase = blockIdx.x * 16 + w * 4;
  for (int rr = 0; rr < 4; ++rr){
    int rloc = rbase + rr;
    int bb = rloc >> 12;           // local batch within chunk
    int n = rloc & 4095;
    int b = b0 + bb;
    const u16* xrow = img + ((size_t)b * SEQ + n) * E_DIM;
    const u16* trow = text + (size_t)b * E_DIM;
    const u16* kvrow = kv + (size_t)rloc * 2048;
    u16* dst1 = attn + ((size_t)bb * 8192 + n) * E_DIM;          // img_out row
    u16* dst2 = attn + ((size_t)bb * 8192 + 4096 + n) * E_DIM;   // text_out row

    // ---------- attention 1: softmax(t_keys . k_it^T / 8) @ v_it ----------
    {
      f32x4 s = fz;
      #pragma unroll
      for (int ks = 0; ks < 2; ++ks){
        bf16x8 a  = *(const bf16x8*)(trow  + l15 * 64 + ks * 32 + quad * 8);
        bf16x8 bk = *(const bf16x8*)(kvrow + l15 * 64 + ks * 32 + quad * 8);
        s = __builtin_amdgcn_mfma_f32_16x16x32_bf16(a, bk, s, 0, 0, 0);
      }
      float p[4];
      softmax16(s, p);
      lds_fence();                     // prior LDS reads done before overwrite
      #pragma unroll
      for (int g2 = 0; g2 < 4; ++g2)
        sPw[(quad * 4 + g2) * 32 + l15] = f2bf(p[g2]);
      lds_fence();                     // writes visible before reads
      bf16x8 aP = bz;
      if (quad < 2) aP = *(const bf16x8*)(sPw + l15 * 32 + quad * 8);
      #pragma unroll
      for (int ni = 0; ni < 4; ++ni){
        bf16x8 bV = bz;
        if (quad < 2){
          short tv[8] __attribute__((aligned(16)));
          #pragma unroll
          for (int j = 0; j < 8; ++j)
            tv[j] = (short)kvrow[1024 + (quad * 8 + j) * 64 + ni * 16 + l15];
          bV = *(const bf16x8*)tv;
        }
        f32x4 o = __builtin_amdgcn_mfma_f32_16x16x32_bf16(aP, bV, fz, 0, 0, 0);
        #pragma unroll
        for (int g2 = 0; g2 < 4; ++g2)
          dst1[(quad * 4 + g2) * 64 + ni * 16 + l15] = f2bf(o[g2]);
      }
    }
    // ---------- attention 2: softmax(img . k_ti^T / 8) @ v_ti ----------
    {
      const u16* ktib = kti + (size_t)b * E_DIM;
      const u16* vtb  = vtiT + (size_t)b * E_DIM;
      f32x4 s = fz;
      #pragma unroll
      for (int ks = 0; ks < 2; ++ks){
        bf16x8 a  = *(const bf16x8*)(xrow + l15 * 64 + ks * 32 + quad * 8);
        bf16x8 bk = *(const bf16x8*)(ktib + l15 * 64 + ks * 32 + quad * 8);
        s = __builtin_amdgcn_mfma_f32_16x16x32_bf16(a, bk, s, 0, 0, 0);
      }
      float p[4];
      softmax16(s, p);
      lds_fence();
      #pragma unroll
      for (int g2 = 0; g2 < 4; ++g2)
        sPw[(quad * 4 + g2) * 32 + l15] = f2bf(p[g2]);
      lds_fence();
      bf16x8 aP = bz;
      if (quad < 2) aP = *(const bf16x8*)(sPw + l15 * 32 + quad * 8);
      #pragma unroll
      for (int ni = 0; ni < 4; ++ni){
        bf16x8 bV = bz;
        if (quad < 2)
          bV = *(const bf16x8*)(vtb + (ni * 16 + l15) * 16 + quad * 8);
        f32x4 o = __builtin_amdgcn_mfma_f32_16x16x32_bf16(aP, bV, fz, 0, 0, 0);
        #pragma unroll
        for (int g2 = 0; g2 < 4; ++g2)
          dst2[(quad * 4 + g2) * 64 + ni * 16 + l15] = f2bf(o[g2]);
      }
    }
  }
}

// ---------------- host ----------------
extern "C" void kernel_launch(void* const* d_in, const int* in_sizes, int n_in,
                              void* d_out, int out_size, void* d_ws, size_t ws_size,
                              hipStream_t stream) {
  const float* img  = (const float*)d_in[0];
  const float* text = (const float*)d_in[1];
  const float* Wkit = (const float*)d_in[2];
  const float* bkit = (const float*)d_in[3];
  const float* Wvit = (const float*)d_in[4];
  const float* bvit = (const float*)d_in[5];
  const float* Wkti = (const float*)d_in[6];
  const float* bkti = (const float*)d_in[7];
  const float* Wvti = (const float*)d_in[8];
  const float* bvti = (const float*)d_in[9];
  const float* Wout = (const float*)d_in[10];
  const float* bout = (const float*)d_in[11];
  float* out = (float*)d_out;

  u16* wsp    = (u16*)d_ws;
  u16* Wt_kv  = wsp;                       // 2048*1024 u16
  u16* Wt_out = Wt_kv + 2048 * 1024;       // 1024*1024
  u16* kti    = Wt_out + 1024 * 1024;      // 8*1024
  u16* vtiT   = kti + 8 * 1024;            // 8*1024
  u16* tb16   = vtiT + 8 * 1024;           // 8*1024
  u16* imgb   = tb16 + 8 * 1024;           // 8*4096*1024
  float* bkv  = (float*)(imgb + (size_t)BATCH * SEQ * E_DIM);  // 2048 fp32
  u16* cbuf   = (u16*)(bkv + 2048);

  // prep (once per launch)
  conv_f2b<<<(BATCH * SEQ * E_DIM) / (256 * 8), 256, 0, stream>>>(img, imgb);
  conv_f2b<<<(BATCH * E_DIM) / (256 * 8), 256, 0, stream>>>(text, tb16);
  prep_transpose<<<dim3(256, 3), 256, 0, stream>>>(Wkit, Wvit, Wout, Wt_kv, Wt_out);
  prep_bias<<<8, 256, 0, stream>>>(bkit, bvit, bkv);
  prep_ti<<<dim3(8, 2), 1024, 0, stream>>>(text, Wkti, bkti, Wvti, bvti, kti, vtiT);

  // one batch per chunk
  for (int c = 0; c < 8; ++c){
    int b0 = c;
    int rows = 4096;
    u16* kvb = cbuf;                           // [rows][2048] bf16
    u16* attnb = cbuf + (size_t)rows * 2048;   // [2*rows][1024] bf16
    // GEMM1: kv_it = img_chunk @ [W_kit|W_vit] + [b_kit|b_vit]  (bf16 out)
    int mt1 = rows / 128, nt1 = 16;
    int G1 = (mt1 < 32) ? mt1 : 32;
    gemm_bt<u16><<<mt1 * nt1, 256, 0, stream>>>(
        imgb + (size_t)b0 * SEQ * E_DIM, Wt_kv, bkv, kvb, nt1, G1, 2048);
    // attention (bf16 out)
    attn_kernel<<<rows / 16, 256, 0, stream>>>(imgb, tb16, kvb, kti, vtiT, attnb, b0);
    // GEMM2: out_chunk = attn @ W_out + b_out  (fp32 out)
    int mt2 = rows * 2 / 128, nt2 = 8;
    int G2 = (mt2 < 64) ? mt2 : 64;
    gemm_bt<float><<<mt2 * nt2, 256, 0, stream>>>(
        attnb, Wt_out, bout, out + (size_t)b0 * 2 * SEQ * E_DIM, nt2, G2, 1024);
  }
}